// Round 13
// baseline (579.948 us; speedup 1.0000x reference)
//
#include <hip/hip_runtime.h>

#define LRELU(x) ((x) > 0.0f ? (x) : 0.01f * (x))
#define UAF __uint_as_float
#define NSLOT 16

#if defined(__has_builtin)
#if __has_builtin(__builtin_amdgcn_fdot2_f32_bf16)
#define HAS_DOT2BF 1
#endif
#endif
#ifndef HAS_DOT2BF
#define HAS_DOT2BF 0
#endif

__device__ inline uint pack_bf16_rne(float x, float y) {
    uint lo = __float_as_uint(x);
    uint hi = __float_as_uint(y);
    lo = (lo + 0x7fffu + ((lo >> 16) & 1u)) >> 16;
    hi = (hi + 0x7fffu + ((hi >> 16) & 1u)) & 0xffff0000u;
    return lo | hi;
}

__device__ inline float dot2bf(uint a, uint b, float c) {
#if HAS_DOT2BF
    typedef __bf16 bf16x2 __attribute__((ext_vector_type(2)));
    return __builtin_amdgcn_fdot2_f32_bf16(__builtin_bit_cast(bf16x2, a),
                                           __builtin_bit_cast(bf16x2, b), c, false);
#else
    c += UAF(a << 16) * UAF(b << 16);
    c += UAF(a & 0xffff0000u) * UAF(b & 0xffff0000u);
    return c;
#endif
}

__global__ void zero_kernel(float* p, int n) {
    int i = blockIdx.x * blockDim.x + threadIdx.x;
    if (i < n) p[i] = 0.0f;
}

// ---------- bucketed CSR build (r8, passing) ----------
__global__ __launch_bounds__(256) void bhist_kernel(const int* __restrict__ dst,
                                                    int* __restrict__ bcnt, int E, int NB) {
    __shared__ int h[512];
    for (int i = threadIdx.x; i < NB; i += 256) h[i] = 0;
    __syncthreads();
    int base = blockIdx.x * 8192;
    int end = min(E, base + 8192);
    for (int e = base + threadIdx.x; e < end; e += 256) atomicAdd(&h[dst[e] >> 8], 1);
    __syncthreads();
    for (int i = threadIdx.x; i < NB; i += 256)
        if (h[i]) atomicAdd(&bcnt[i], h[i]);
}

__global__ __launch_bounds__(512) void bscan_kernel(const int* __restrict__ bcnt,
                                                    int* __restrict__ boff,
                                                    int* __restrict__ bcur, int NB) {
    __shared__ int sh[512];
    int t = threadIdx.x;
    int v = (t < NB) ? bcnt[t] : 0;
    sh[t] = v;
    __syncthreads();
    for (int o = 1; o < 512; o <<= 1) {
        int u = (t >= o) ? sh[t - o] : 0;
        __syncthreads();
        sh[t] += u;
        __syncthreads();
    }
    if (t < NB) {
        boff[t] = sh[t] - v;
        bcur[t] = sh[t] - v;
    }
}

__global__ __launch_bounds__(256) void bscatter_kernel(const int* __restrict__ src,
                                                       const int* __restrict__ dst,
                                                       int* __restrict__ bcur,
                                                       uint* __restrict__ pairs, int E, int NB) {
    __shared__ int h[512];
    __shared__ int bbase[512];
    for (int i = threadIdx.x; i < NB; i += 256) h[i] = 0;
    __syncthreads();
    int base = blockIdx.x * 8192;
    int end = min(E, base + 8192);
    for (int e = base + threadIdx.x; e < end; e += 256) atomicAdd(&h[dst[e] >> 8], 1);
    __syncthreads();
    for (int i = threadIdx.x; i < NB; i += 256) {
        bbase[i] = h[i] ? atomicAdd(&bcur[i], h[i]) : 0;
        h[i] = 0;
    }
    __syncthreads();
    for (int e = base + threadIdx.x; e < end; e += 256) {
        int d = dst[e];
        int b = d >> 8;
        int o = atomicAdd(&h[b], 1);
        pairs[bbase[b] + o] = ((uint)src[e] << 8) | (uint)(d & 255);
    }
}

__global__ __launch_bounds__(256) void bcsr_kernel(const uint* __restrict__ pairs,
                                                   const int* __restrict__ boff,
                                                   int* __restrict__ ptr, int* __restrict__ cnt,
                                                   int* __restrict__ nbr, int N, int NB, int E) {
    __shared__ int h[256];
    __shared__ int sc[256];
    int b = blockIdx.x;
    int lo = boff[b];
    int hi = (b + 1 < NB) ? boff[b + 1] : E;
    int t = threadIdx.x;
    h[t] = 0;
    __syncthreads();
    for (int i = lo + t; i < hi; i += 256) atomicAdd(&h[pairs[i] & 255u], 1);
    __syncthreads();
    int v = h[t];
    sc[t] = v;
    __syncthreads();
    for (int o = 1; o < 256; o <<= 1) {
        int u = (t >= o) ? sc[t - o] : 0;
        __syncthreads();
        sc[t] += u;
        __syncthreads();
    }
    int excl = sc[t] - v;
    int node = (b << 8) + t;
    if (node < N) {
        ptr[node] = lo + excl;
        cnt[node] = v;
    }
    __syncthreads();
    h[t] = excl;
    __syncthreads();
    for (int i = lo + t; i < hi; i += 256) {
        uint p = pairs[i];
        int ld = p & 255u;
        int o = atomicAdd(&h[ld], 1);
        nbr[lo + o] = (int)(p >> 8);
    }
}

// ---------- pre-pack W1/W2 (6 x 64x64) to bf16 k-pair layout [mat][kp*64+c] ----------
__global__ void packw_kernel(const float* __restrict__ W1, const float* __restrict__ W2,
                             uint* __restrict__ Wp) {
    int id = blockIdx.x * blockDim.x + threadIdx.x;
    if (id >= 6 * 2048) return;
    int mat = id >> 11;
    int r = id & 2047;
    int kp = r >> 6, c = r & 63;
    const float* Ws = (mat < 3) ? (W1 + (size_t)mat * 4096) : (W2 + (size_t)(mat - 3) * 4096);
    Wp[id] = pack_bf16_rne(Ws[(size_t)(2 * kp) * 64 + c], Ws[(size_t)(2 * kp + 1) * 64 + c]);
}

// ---------- fp32 -> bf16 quarter-planes (layer 0 input) ----------
// plane q (N*8 uints) holds features [16q,16q+16) of all rows
__global__ __launch_bounds__(256) void to_bf16_kernel(const float* __restrict__ in,
                                                      uint* __restrict__ planes, int n8,
                                                      int NQ) {
    int i = blockIdx.x * blockDim.x + threadIdx.x;
    if (i >= n8) return;
    float4 a = *(const float4*)&in[(size_t)i * 8];
    float4 b = *(const float4*)&in[(size_t)i * 8 + 4];
    uint4 p = make_uint4(pack_bf16_rne(a.x, a.y), pack_bf16_rne(a.z, a.w),
                         pack_bf16_rne(b.x, b.y), pack_bf16_rne(b.z, b.w));
    int node = i >> 3;
    int oct = i & 7;  // features oct*8..oct*8+7
    int q = oct >> 1;
    int off = (oct & 1) * 4;
    *(uint4*)&planes[(size_t)q * NQ + (size_t)node * 8 + off] = p;
}

// ---------- aggregation over quarter-planes ----------
// wave handles (node, quarter); quarter = blockIdx&3 so round-robin XCD dispatch pins
// each XCD to ONE 3.2MB plane (L2-resident; r12: full table re-streamed 86MB/gather).
// 8 lanes per neighbor slot x 8 slots in flight; shfl_xor slot-reduce.
template <bool ACT>
__global__ __launch_bounds__(256) void gather_kernel(
    const uint* __restrict__ planes, const int* __restrict__ ptr, const int* __restrict__ cnt,
    const int* __restrict__ nbr, const float* __restrict__ eps_gin, int layer,
    const float* __restrict__ scale, const float* __restrict__ shift, uint* __restrict__ agg,
    int N, int NQ) {
    int q = blockIdx.x & 3;
    int node = (blockIdx.x >> 2) * 4 + (threadIdx.x >> 6);
    if (node >= N) return;
    const uint* tb = planes + (size_t)q * NQ;
    int lane = threadIdx.x & 63;
    int sub = lane >> 3;  // neighbor slot 0..7
    int fl = lane & 7;    // uint (feature-pair) within quarter
    float sc0 = 1.0f, sh0 = 0.0f, sc1 = 1.0f, sh1 = 0.0f;
    if (ACT) {
        int p = 2 * (q * 8 + fl);
        sc0 = scale[p + 0];
        sh0 = shift[p + 0];
        sc1 = scale[p + 1];
        sh1 = shift[p + 1];
    }
    int start = ptr[node];
    int deg = cnt[node];
    float a0 = 0.0f, a1 = 0.0f;
    int j = sub;
    for (; j + 8 < deg; j += 16) {  // 2-deep per slot
        int nA = nbr[start + j];
        int nB = nbr[start + j + 8];
        uint vA = tb[(size_t)nA * 8 + fl];
        uint vB = tb[(size_t)nB * 8 + fl];
        float fA0 = UAF(vA << 16), fA1 = UAF(vA & 0xffff0000u);
        float fB0 = UAF(vB << 16), fB1 = UAF(vB & 0xffff0000u);
        if (ACT) {
            fA0 = LRELU(fA0 * sc0 + sh0);
            fA1 = LRELU(fA1 * sc1 + sh1);
            fB0 = LRELU(fB0 * sc0 + sh0);
            fB1 = LRELU(fB1 * sc1 + sh1);
        }
        a0 += fA0 + fB0;
        a1 += fA1 + fB1;
    }
    for (; j < deg; j += 8) {
        int nA = nbr[start + j];
        uint vA = tb[(size_t)nA * 8 + fl];
        float fA0 = UAF(vA << 16), fA1 = UAF(vA & 0xffff0000u);
        if (ACT) {
            fA0 = LRELU(fA0 * sc0 + sh0);
            fA1 = LRELU(fA1 * sc1 + sh1);
        }
        a0 += fA0;
        a1 += fA1;
    }
    // reduce across the 8 slots
    for (int o = 8; o < 64; o <<= 1) {
        a0 += __shfl_xor(a0, o);
        a1 += __shfl_xor(a1, o);
    }
    if (sub == 0) {
        uint vs = tb[(size_t)node * 8 + fl];
        float s0 = UAF(vs << 16), s1 = UAF(vs & 0xffff0000u);
        if (ACT) {
            s0 = LRELU(s0 * sc0 + sh0);
            s1 = LRELU(s1 * sc1 + sh1);
        }
        float ep = 1.0f + eps_gin[layer];
        a0 += ep * s0;
        a1 += ep * s1;
        agg[(size_t)node * 32 + q * 8 + fl] = pack_bf16_rne(a0, a1);
    }
}

// reduce NSLOT-slotted sums -> BN scale/shift
__global__ void finalize_kernel(const float* __restrict__ sums, const float* __restrict__ g,
                                const float* __restrict__ be, float* __restrict__ scale,
                                float* __restrict__ shift, int C, float invN) {
    int d = threadIdx.x;
    if (d >= C) return;
    float s = 0.0f, s2 = 0.0f;
    for (int k = 0; k < NSLOT; k++) {
        s += sums[k * 2 * C + d];
        s2 += sums[k * 2 * C + C + d];
    }
    float mean = s * invN;
    float var = s2 * invN - mean * mean;
    float sc = g[d] * rsqrtf(var + 1e-5f);
    scale[d] = sc;
    shift[d] = be[d] - mean * sc;
}

// ---------- bf16-dot gemm (COLS=64): pre-packed W; input agg(bf16) or h1(fp32)+BN;
// output quarter-planes (OUTB) or fp32; slotted stats ----------
template <bool INBN, bool OUTB, int MINW>
__global__ __launch_bounds__(256, MINW) void gemm_bf16_kernel(
    const uint* __restrict__ inb, const float* __restrict__ inf, const uint* __restrict__ Wp,
    const float* __restrict__ bias, const float* __restrict__ scale,
    const float* __restrict__ shift, uint* __restrict__ outb, float* __restrict__ outf,
    float* __restrict__ sums, int nrows, int NQ) {
    constexpr int COLS = 64;
    __shared__ uint smem[32 * 68 + 32 * COLS];
    uint* inT = smem;
    uint* wsb = smem + 32 * 68;
    int t = threadIdx.x;
    int row0 = blockIdx.x * 64;

    if (!INBN) {
        for (int i = 0; i < 2; i++) {
            int f = t + 256 * i;
            int r = f >> 3, q = f & 7;
            int gr = row0 + r;
            uint4 v = make_uint4(0, 0, 0, 0);
            if (gr < nrows) v = *(const uint4*)&inb[(size_t)gr * 32 + q * 4];
            inT[(4 * q + 0) * 68 + r] = v.x;
            inT[(4 * q + 1) * 68 + r] = v.y;
            inT[(4 * q + 2) * 68 + r] = v.z;
            inT[(4 * q + 3) * 68 + r] = v.w;
        }
    } else {
        for (int i = 0; i < 4; i++) {
            int f = t + 256 * i;
            int r = f >> 4, q = f & 15;
            int gr = row0 + r;
            float4 v = make_float4(0.f, 0.f, 0.f, 0.f);
            if (gr < nrows) v = *(const float4*)&inf[(size_t)gr * 64 + q * 4];
            int d = 4 * q;
            float e0 = LRELU(v.x * scale[d + 0] + shift[d + 0]);
            float e1 = LRELU(v.y * scale[d + 1] + shift[d + 1]);
            float e2 = LRELU(v.z * scale[d + 2] + shift[d + 2]);
            float e3 = LRELU(v.w * scale[d + 3] + shift[d + 3]);
            inT[(2 * q + 0) * 68 + r] = pack_bf16_rne(e0, e1);
            inT[(2 * q + 1) * 68 + r] = pack_bf16_rne(e2, e3);
        }
    }
    for (int i = 0; i < 2; i++) {
        int f = (t + 256 * i) * 4;
        *(uint4*)&wsb[f] = *(const uint4*)&Wp[f];
    }
    __syncthreads();

    int rg = t >> 4, cg = t & 15;
    int r0 = rg * 4, c0 = cg * 4;
    float acc[4][4];
#pragma unroll
    for (int r = 0; r < 4; r++)
#pragma unroll
        for (int c = 0; c < 4; c++) acc[r][c] = 0.0f;

#pragma unroll 8
    for (int kp = 0; kp < 32; kp++) {
        uint4 a = *(const uint4*)&inT[kp * 68 + r0];
        uint av[4] = {a.x, a.y, a.z, a.w};
        uint4 w = *(const uint4*)&wsb[kp * COLS + c0];
        uint wv[4] = {w.x, w.y, w.z, w.w};
#pragma unroll
        for (int r = 0; r < 4; r++)
#pragma unroll
            for (int c = 0; c < 4; c++) acc[r][c] = dot2bf(av[r], wv[c], acc[r][c]);
    }

    float ps[4], ps2[4];
#pragma unroll
    for (int c = 0; c < 4; c++) ps[c] = ps2[c] = 0.0f;
    float4 bv = *(const float4*)&bias[c0];
#pragma unroll
    for (int r = 0; r < 4; r++) {
        int gr = row0 + r0 + r;
        if (gr < nrows) {
            float o0 = acc[r][0] + bv.x;
            float o1 = acc[r][1] + bv.y;
            float o2 = acc[r][2] + bv.z;
            float o3 = acc[r][3] + bv.w;
            if (OUTB) {
                uint2 pk = make_uint2(pack_bf16_rne(o0, o1), pack_bf16_rne(o2, o3));
                *(uint2*)&outb[(size_t)(c0 >> 4) * NQ + (size_t)gr * 8 + ((c0 & 15) >> 1)] = pk;
            } else {
                *(float4*)&outf[(size_t)gr * 64 + c0] = make_float4(o0, o1, o2, o3);
            }
            ps[0] += o0;
            ps2[0] += o0 * o0;
            ps[1] += o1;
            ps2[1] += o1 * o1;
            ps[2] += o2;
            ps2[2] += o2 * o2;
            ps[3] += o3;
            ps2[3] += o3 * o3;
        }
    }

    if (sums == nullptr) return;

    __syncthreads();
    float* red = (float*)smem;
    float* red2 = red + 16 * COLS;
    *(float4*)&red[rg * COLS + c0] = *(float4*)&ps[0];
    *(float4*)&red2[rg * COLS + c0] = *(float4*)&ps2[0];
    __syncthreads();
    if (t < COLS) {
        float s = 0.0f, s2 = 0.0f;
#pragma unroll
        for (int j = 0; j < 16; j++) {
            s += red[j * COLS + t];
            s2 += red2[j * COLS + t];
        }
        int slot = blockIdx.x & (NSLOT - 1);
        atomicAdd(&sums[slot * 2 * COLS + t], s);
        atomicAdd(&sums[slot * 2 * COLS + COLS + t], s2);
    }
}

// ---------- head gemm, full fp32: HF = X @ Wf1 + bf1, slotted col-stats ----------
__global__ __launch_bounds__(256, 4) void gemm_f32_head_kernel(const float* __restrict__ in,
                                                               const float* __restrict__ W,
                                                               const float* __restrict__ bias,
                                                               float* __restrict__ out,
                                                               float* __restrict__ sums,
                                                               int nrows) {
    constexpr int COLS = 128;
    __shared__ float inT[64][68];
    __shared__ float ws[64][COLS];
    int t = threadIdx.x;
    int row0 = blockIdx.x * 64;

    for (int i = 0; i < 4; i++) {
        int f = t + 256 * i;
        int r = f >> 4, ch = f & 15;
        int gr = row0 + r;
        float4 v = make_float4(0.f, 0.f, 0.f, 0.f);
        if (gr < nrows) v = *(const float4*)&in[(size_t)gr * 64 + ch * 4];
        inT[ch * 4 + 0][r] = v.x;
        inT[ch * 4 + 1][r] = v.y;
        inT[ch * 4 + 2][r] = v.z;
        inT[ch * 4 + 3][r] = v.w;
    }
    for (int i = 0; i < COLS / 16; i++) {
        int f = t + 256 * i;
        int k = f / (COLS / 4), c4 = f % (COLS / 4);
        *(float4*)&ws[k][c4 * 4] = *(const float4*)&W[(size_t)k * COLS + c4 * 4];
    }
    __syncthreads();

    int rg = t >> 4, cg = t & 15;
    int r0 = rg * 4, c0 = cg * 4;
    float acc[4][8];
#pragma unroll
    for (int r = 0; r < 4; r++)
#pragma unroll
        for (int c = 0; c < 8; c++) acc[r][c] = 0.0f;

#pragma unroll 16
    for (int k = 0; k < 64; k++) {
        float4 a = *(const float4*)&inT[k][r0];
        float ar[4] = {a.x, a.y, a.z, a.w};
#pragma unroll
        for (int jj = 0; jj < 2; jj++) {
            float4 w4 = *(const float4*)&ws[k][c0 + jj * 64];
            float wr[4] = {w4.x, w4.y, w4.z, w4.w};
#pragma unroll
            for (int r = 0; r < 4; r++)
#pragma unroll
                for (int c = 0; c < 4; c++) acc[r][jj * 4 + c] += ar[r] * wr[c];
        }
    }

    float ps[8], ps2[8];
#pragma unroll
    for (int c = 0; c < 8; c++) ps[c] = ps2[c] = 0.0f;
#pragma unroll
    for (int r = 0; r < 4; r++) {
        int gr = row0 + r0 + r;
        if (gr < nrows) {
#pragma unroll
            for (int jj = 0; jj < 2; jj++) {
                float4 bv = *(const float4*)&bias[c0 + jj * 64];
                float4 o = make_float4(acc[r][jj * 4 + 0] + bv.x, acc[r][jj * 4 + 1] + bv.y,
                                       acc[r][jj * 4 + 2] + bv.z, acc[r][jj * 4 + 3] + bv.w);
                *(float4*)&out[(size_t)gr * COLS + c0 + jj * 64] = o;
                ps[jj * 4 + 0] += o.x;
                ps2[jj * 4 + 0] += o.x * o.x;
                ps[jj * 4 + 1] += o.y;
                ps2[jj * 4 + 1] += o.y * o.y;
                ps[jj * 4 + 2] += o.z;
                ps2[jj * 4 + 2] += o.z * o.z;
                ps[jj * 4 + 3] += o.w;
                ps2[jj * 4 + 3] += o.w * o.w;
            }
        }
    }

    __syncthreads();
    float* red = &inT[0][0];
    float* red2 = red + 16 * COLS;
#pragma unroll
    for (int jj = 0; jj < 2; jj++) {
        *(float4*)&red[rg * COLS + c0 + jj * 64] = *(float4*)&ps[jj * 4];
        *(float4*)&red2[rg * COLS + c0 + jj * 64] = *(float4*)&ps2[jj * 4];
    }
    __syncthreads();
    if (t < COLS) {
        float s = 0.0f, s2 = 0.0f;
#pragma unroll
        for (int j = 0; j < 16; j++) {
            s += red[j * COLS + t];
            s2 += red2[j * COLS + t];
        }
        int slot = blockIdx.x & (NSLOT - 1);
        atomicAdd(&sums[slot * 2 * COLS + t], s);
        atomicAdd(&sums[slot * 2 * COLS + COLS + t], s2);
    }
}

// one wave per row; hf fp32 (N x 128)
__global__ void head_out_kernel(const float* __restrict__ hf, const float* __restrict__ scale,
                                const float* __restrict__ shift, const float* __restrict__ Wf2,
                                const float* __restrict__ bf2, float* __restrict__ out,
                                int nrows) {
    int gtid = blockIdx.x * blockDim.x + threadIdx.x;
    int wid = gtid >> 6;
    int l = threadIdx.x & 63;
    if (wid >= nrows) return;
    float v0 = hf[(size_t)wid * 128 + l];
    float v1 = hf[(size_t)wid * 128 + 64 + l];
    v0 = LRELU(v0 * scale[l] + shift[l]);
    v1 = LRELU(v1 * scale[64 + l] + shift[64 + l]);
    float p = v0 * Wf2[l] + v1 * Wf2[64 + l];
    for (int o = 32; o > 0; o >>= 1) p += __shfl_down(p, o);
    if (l == 0) out[wid] = p + bf2[0];
}

extern "C" void kernel_launch(void* const* d_in, const int* in_sizes, int n_in, void* d_out,
                              int out_size, void* d_ws, size_t ws_size, hipStream_t stream) {
    const float* x = (const float*)d_in[0];
    const int* esrc = (const int*)d_in[1];
    const int* edst = (const int*)d_in[2];
    const float* W1 = (const float*)d_in[3];
    const float* b1 = (const float*)d_in[4];
    const float* g1 = (const float*)d_in[5];
    const float* be1 = (const float*)d_in[6];
    const float* W2 = (const float*)d_in[7];
    const float* b2 = (const float*)d_in[8];
    const float* eps_gin = (const float*)d_in[9];
    const float* g_bn = (const float*)d_in[10];
    const float* b_bn = (const float*)d_in[11];
    const float* Wf1 = (const float*)d_in[12];
    const float* bf1 = (const float*)d_in[13];
    const float* gf = (const float*)d_in[14];
    const float* bef = (const float*)d_in[15];
    const float* Wf2 = (const float*)d_in[16];
    const float* bf2 = (const float*)d_in[17];
    float* out = (float*)d_out;

    int N = in_sizes[0] / 64;
    int E = in_sizes[1];
    int NB = (N + 255) / 256;
    int NQ = N * 8;  // uints per plane
    float invN = 1.0f / (float)N;

    float* ws = (float*)d_ws;
    size_t ND = (size_t)N * 64;
    // region A: 4 bf16 quarter-planes (lower half) + pairs (upper, build-only); later X fp32
    uint* planes = (uint*)ws;  // 4 * NQ uints
    uint* pairs = (uint*)(ws + ND / 2);
    float* X = ws;
    float* h1 = ws + ND;               // region B: h1 fp32
    uint* agg = (uint*)(ws + 2 * ND);  // region C: agg bf16 (lower half)
    float* HF = ws + ND;               // HF fp32 spans B+C after h1/agg dead
    float* stats = ws + 3 * ND;
    float* ssarea = stats + 5 * NSLOT * 128 + NSLOT * 256;
    int* ibase = (int*)(ssarea + 5 * 128 + 256);
    int* bcnt = ibase;
    int* bcur = ibase + 512;
    int* boff = ibase + 1024;
    int* cnt = ibase + 1536;
    int* ptr = cnt + N;
    int* nbr = ptr + N;
    uint* Wp = (uint*)(nbr + E);  // 6*2048 uints packed weights

    int nzero = 5 * NSLOT * 128 + NSLOT * 256 + 5 * 128 + 256 + 512;
    zero_kernel<<<(nzero + 255) / 256, 256, 0, stream>>>(stats, nzero);

    int eb = (E + 8191) / 8192;
    bhist_kernel<<<eb, 256, 0, stream>>>(edst, bcnt, E, NB);
    bscan_kernel<<<1, 512, 0, stream>>>(bcnt, boff, bcur, NB);
    bscatter_kernel<<<eb, 256, 0, stream>>>(esrc, edst, bcur, pairs, E, NB);
    bcsr_kernel<<<NB, 256, 0, stream>>>(pairs, boff, ptr, cnt, nbr, N, NB, E);
    packw_kernel<<<(6 * 2048 + 255) / 256, 256, 0, stream>>>(W1, W2, Wp);

    int n8 = N * 8;
    int gg = (N + 63) / 64;
    int gblocks = ((N + 3) / 4) * 4;  // 4 waves/block, one (node,quarter) per wave
    to_bf16_kernel<<<(n8 + 255) / 256, 256, 0, stream>>>(x, planes, n8, NQ);

    for (int i = 0; i < 3; i++) {
        float* st = stats + (size_t)(2 * i) * NSLOT * 128;
        float* so = stats + (size_t)(2 * i + 1) * NSLOT * 128;
        float* st_ss = ssarea + (size_t)(2 * i) * 128;
        float* so_ss = ssarea + (size_t)(2 * i + 1) * 128;
        if (i == 0) {
            gather_kernel<false><<<gblocks, 256, 0, stream>>>(
                planes, ptr, cnt, nbr, eps_gin, i, nullptr, nullptr, agg, N, NQ);
        } else {
            float* sp_ss = ssarea + (size_t)(2 * (i - 1) + 1) * 128;
            gather_kernel<true><<<gblocks, 256, 0, stream>>>(
                planes, ptr, cnt, nbr, eps_gin, i, sp_ss, sp_ss + 64, agg, N, NQ);
        }
        gemm_bf16_kernel<false, false, 6><<<gg, 256, 0, stream>>>(
            agg, nullptr, Wp + (size_t)i * 2048, b1 + (size_t)i * 64, nullptr, nullptr, nullptr,
            h1, st, N, NQ);
        finalize_kernel<<<1, 64, 0, stream>>>(st, g1 + (size_t)i * 64, be1 + (size_t)i * 64,
                                              st_ss, st_ss + 64, 64, invN);
        if (i < 2) {
            gemm_bf16_kernel<true, true, 6><<<gg, 256, 0, stream>>>(
                nullptr, h1, Wp + (size_t)(3 + i) * 2048, b2 + (size_t)i * 64, st_ss, st_ss + 64,
                planes, nullptr, so, N, NQ);
            finalize_kernel<<<1, 64, 0, stream>>>(so, g_bn + (size_t)i * 64,
                                                  b_bn + (size_t)i * 64, so_ss, so_ss + 64, 64,
                                                  invN);
        } else {
            gemm_bf16_kernel<true, false, 6><<<gg, 256, 0, stream>>>(
                nullptr, h1, Wp + (size_t)(3 + i) * 2048, b2 + (size_t)i * 64, st_ss, st_ss + 64,
                nullptr, X, nullptr, N, NQ);
        }
    }

    float* sf = stats + (size_t)5 * NSLOT * 128;
    float* sf_ss = ssarea + 5 * 128;
    gemm_f32_head_kernel<<<gg, 256, 0, stream>>>(X, Wf1, bf1, HF, sf, N);
    finalize_kernel<<<1, 128, 0, stream>>>(sf, gf, bef, sf_ss, sf_ss + 128, 128, invN);
    head_out_kernel<<<(N + 3) / 4, 256, 0, stream>>>(HF, sf_ss, sf_ss + 128, Wf2, bf2, out, N);
}

// Round 14
// 376.448 us; speedup vs baseline: 1.5406x; 1.5406x over previous
//
#include <hip/hip_runtime.h>

#define LRELU(x) ((x) > 0.0f ? (x) : 0.01f * (x))
#define UAF __uint_as_float
#define NSLOT 16

#if defined(__has_builtin)
#if __has_builtin(__builtin_amdgcn_fdot2_f32_bf16)
#define HAS_DOT2BF 1
#endif
#endif
#ifndef HAS_DOT2BF
#define HAS_DOT2BF 0
#endif

__device__ inline uint pack_bf16_rne(float x, float y) {
    uint lo = __float_as_uint(x);
    uint hi = __float_as_uint(y);
    lo = (lo + 0x7fffu + ((lo >> 16) & 1u)) >> 16;
    hi = (hi + 0x7fffu + ((hi >> 16) & 1u)) & 0xffff0000u;
    return lo | hi;
}

__device__ inline float dot2bf(uint a, uint b, float c) {
#if HAS_DOT2BF
    typedef __bf16 bf16x2 __attribute__((ext_vector_type(2)));
    return __builtin_amdgcn_fdot2_f32_bf16(__builtin_bit_cast(bf16x2, a),
                                           __builtin_bit_cast(bf16x2, b), c, false);
#else
    c += UAF(a << 16) * UAF(b << 16);
    c += UAF(a & 0xffff0000u) * UAF(b & 0xffff0000u);
    return c;
#endif
}

__global__ void zero_kernel(float* p, int n) {
    int i = blockIdx.x * blockDim.x + threadIdx.x;
    if (i < n) p[i] = 0.0f;
}

// ---------- bucketed CSR build (r8, passing) ----------
__global__ __launch_bounds__(256) void bhist_kernel(const int* __restrict__ dst,
                                                    int* __restrict__ bcnt, int E, int NB) {
    __shared__ int h[512];
    for (int i = threadIdx.x; i < NB; i += 256) h[i] = 0;
    __syncthreads();
    int base = blockIdx.x * 8192;
    int end = min(E, base + 8192);
    for (int e = base + threadIdx.x; e < end; e += 256) atomicAdd(&h[dst[e] >> 8], 1);
    __syncthreads();
    for (int i = threadIdx.x; i < NB; i += 256)
        if (h[i]) atomicAdd(&bcnt[i], h[i]);
}

__global__ __launch_bounds__(512) void bscan_kernel(const int* __restrict__ bcnt,
                                                    int* __restrict__ boff,
                                                    int* __restrict__ bcur, int NB) {
    __shared__ int sh[512];
    int t = threadIdx.x;
    int v = (t < NB) ? bcnt[t] : 0;
    sh[t] = v;
    __syncthreads();
    for (int o = 1; o < 512; o <<= 1) {
        int u = (t >= o) ? sh[t - o] : 0;
        __syncthreads();
        sh[t] += u;
        __syncthreads();
    }
    if (t < NB) {
        boff[t] = sh[t] - v;
        bcur[t] = sh[t] - v;
    }
}

__global__ __launch_bounds__(256) void bscatter_kernel(const int* __restrict__ src,
                                                       const int* __restrict__ dst,
                                                       int* __restrict__ bcur,
                                                       uint* __restrict__ pairs, int E, int NB) {
    __shared__ int h[512];
    __shared__ int bbase[512];
    for (int i = threadIdx.x; i < NB; i += 256) h[i] = 0;
    __syncthreads();
    int base = blockIdx.x * 8192;
    int end = min(E, base + 8192);
    for (int e = base + threadIdx.x; e < end; e += 256) atomicAdd(&h[dst[e] >> 8], 1);
    __syncthreads();
    for (int i = threadIdx.x; i < NB; i += 256) {
        bbase[i] = h[i] ? atomicAdd(&bcur[i], h[i]) : 0;
        h[i] = 0;
    }
    __syncthreads();
    for (int e = base + threadIdx.x; e < end; e += 256) {
        int d = dst[e];
        int b = d >> 8;
        int o = atomicAdd(&h[b], 1);
        pairs[bbase[b] + o] = ((uint)src[e] << 8) | (uint)(d & 255);
    }
}

__global__ __launch_bounds__(256) void bcsr_kernel(const uint* __restrict__ pairs,
                                                   const int* __restrict__ boff,
                                                   int* __restrict__ ptr, int* __restrict__ cnt,
                                                   int* __restrict__ nbr, int N, int NB, int E) {
    __shared__ int h[256];
    __shared__ int sc[256];
    int b = blockIdx.x;
    int lo = boff[b];
    int hi = (b + 1 < NB) ? boff[b + 1] : E;
    int t = threadIdx.x;
    h[t] = 0;
    __syncthreads();
    for (int i = lo + t; i < hi; i += 256) atomicAdd(&h[pairs[i] & 255u], 1);
    __syncthreads();
    int v = h[t];
    sc[t] = v;
    __syncthreads();
    for (int o = 1; o < 256; o <<= 1) {
        int u = (t >= o) ? sc[t - o] : 0;
        __syncthreads();
        sc[t] += u;
        __syncthreads();
    }
    int excl = sc[t] - v;
    int node = (b << 8) + t;
    if (node < N) {
        ptr[node] = lo + excl;
        cnt[node] = v;
    }
    __syncthreads();
    h[t] = excl;
    __syncthreads();
    for (int i = lo + t; i < hi; i += 256) {
        uint p = pairs[i];
        int ld = p & 255u;
        int o = atomicAdd(&h[ld], 1);
        nbr[lo + o] = (int)(p >> 8);
    }
}

// ---------- pre-pack W1/W2 (6 x 64x64) to bf16 k-pair layout [mat][kp*64+c] ----------
__global__ void packw_kernel(const float* __restrict__ W1, const float* __restrict__ W2,
                             uint* __restrict__ Wp) {
    int id = blockIdx.x * blockDim.x + threadIdx.x;
    if (id >= 6 * 2048) return;
    int mat = id >> 11;
    int r = id & 2047;
    int kp = r >> 6, c = r & 63;
    const float* Ws = (mat < 3) ? (W1 + (size_t)mat * 4096) : (W2 + (size_t)(mat - 3) * 4096);
    Wp[id] = pack_bf16_rne(Ws[(size_t)(2 * kp) * 64 + c], Ws[(size_t)(2 * kp + 1) * 64 + c]);
}

// ---------- fp32 -> packed bf16 table (layer 0 input) ----------
__global__ __launch_bounds__(256) void to_bf16_kernel(const float* __restrict__ in,
                                                      uint* __restrict__ table, int n8) {
    int i = blockIdx.x * blockDim.x + threadIdx.x;
    if (i >= n8) return;
    float4 a = *(const float4*)&in[(size_t)i * 8];
    float4 b = *(const float4*)&in[(size_t)i * 8 + 4];
    uint4 p = make_uint4(pack_bf16_rne(a.x, a.y), pack_bf16_rne(a.z, a.w),
                         pack_bf16_rne(b.x, b.y), pack_bf16_rne(b.z, b.w));
    *(uint4*)&table[(size_t)i * 4] = p;
}

// reduce NSLOT-slotted sums -> BN scale/shift
__global__ void finalize_kernel(const float* __restrict__ sums, const float* __restrict__ g,
                                const float* __restrict__ be, float* __restrict__ scale,
                                float* __restrict__ shift, int C, float invN) {
    int d = threadIdx.x;
    if (d >= C) return;
    float s = 0.0f, s2 = 0.0f;
    for (int k = 0; k < NSLOT; k++) {
        s += sums[k * 2 * C + d];
        s2 += sums[k * 2 * C + C + d];
    }
    float mean = s * invN;
    float var = s2 * invN - mean * mean;
    float sc = g[d] * rsqrtf(var + 1e-5f);
    scale[d] = sc;
    shift[d] = be[d] - mean * sc;
}

// ---------- aggregation: one 64-lane wave per node; packed-bf16 in and out (r12) ----------
template <bool ACT>
__global__ __launch_bounds__(256) void gather_kernel(
    const uint* __restrict__ tb, const int* __restrict__ ptr, const int* __restrict__ cnt,
    const int* __restrict__ nbr, const float* __restrict__ eps_gin, int layer,
    const float* __restrict__ scale, const float* __restrict__ shift, uint* __restrict__ agg,
    int N) {
    int gtid = blockIdx.x * blockDim.x + threadIdx.x;
    int node = gtid >> 6;
    if (node >= N) return;
    int lane = threadIdx.x & 63;
    int half = lane >> 5;
    int sl = lane & 31;
    float sc0 = 1.0f, sh0 = 0.0f, sc1 = 1.0f, sh1 = 0.0f;
    if (ACT) {
        sc0 = scale[2 * sl + 0];
        sh0 = shift[2 * sl + 0];
        sc1 = scale[2 * sl + 1];
        sh1 = shift[2 * sl + 1];
    }
    int start = ptr[node];
    int deg = cnt[node];
    float a0 = 0.0f, a1 = 0.0f;
    int j = half;
    for (; j + 14 < deg; j += 16) {  // 8 independent row loads per half
        int ni[8];
        uint vv[8];
#pragma unroll
        for (int q = 0; q < 8; q++) ni[q] = nbr[start + j + 2 * q];
#pragma unroll
        for (int q = 0; q < 8; q++) vv[q] = tb[(size_t)ni[q] * 32 + sl];
#pragma unroll
        for (int q = 0; q < 8; q++) {
            float f0 = UAF(vv[q] << 16), f1 = UAF(vv[q] & 0xffff0000u);
            if (ACT) {
                f0 = LRELU(f0 * sc0 + sh0);
                f1 = LRELU(f1 * sc1 + sh1);
            }
            a0 += f0;
            a1 += f1;
        }
    }
    for (; j + 6 < deg; j += 8) {
        int ni[4];
        uint vv[4];
#pragma unroll
        for (int q = 0; q < 4; q++) ni[q] = nbr[start + j + 2 * q];
#pragma unroll
        for (int q = 0; q < 4; q++) vv[q] = tb[(size_t)ni[q] * 32 + sl];
#pragma unroll
        for (int q = 0; q < 4; q++) {
            float f0 = UAF(vv[q] << 16), f1 = UAF(vv[q] & 0xffff0000u);
            if (ACT) {
                f0 = LRELU(f0 * sc0 + sh0);
                f1 = LRELU(f1 * sc1 + sh1);
            }
            a0 += f0;
            a1 += f1;
        }
    }
    for (; j < deg; j += 2) {
        uint vA = tb[(size_t)nbr[start + j] * 32 + sl];
        float f0 = UAF(vA << 16), f1 = UAF(vA & 0xffff0000u);
        if (ACT) {
            f0 = LRELU(f0 * sc0 + sh0);
            f1 = LRELU(f1 * sc1 + sh1);
        }
        a0 += f0;
        a1 += f1;
    }
    a0 += __shfl(a0, lane ^ 32);
    a1 += __shfl(a1, lane ^ 32);
    uint vs = tb[(size_t)node * 32 + sl];
    float s0 = UAF(vs << 16), s1 = UAF(vs & 0xffff0000u);
    if (ACT) {
        s0 = LRELU(s0 * sc0 + sh0);
        s1 = LRELU(s1 * sc1 + sh1);
    }
    float ep = 1.0f + eps_gin[layer];
    a0 += ep * s0;
    a1 += ep * s1;
    if (half == 0) agg[(size_t)node * 32 + sl] = pack_bf16_rne(a0, a1);
}

// ---------- bf16-dot gemm (COLS=64): pre-packed W; input agg(bf16) or h1(fp32)+BN;
// output bf16 table or fp32; slotted stats (r12) ----------
template <bool INBN, bool OUTB, int MINW>
__global__ __launch_bounds__(256, MINW) void gemm_bf16_kernel(
    const uint* __restrict__ inb, const float* __restrict__ inf, const uint* __restrict__ Wp,
    const float* __restrict__ bias, const float* __restrict__ scale,
    const float* __restrict__ shift, uint* __restrict__ outb, float* __restrict__ outf,
    float* __restrict__ sums, int nrows) {
    constexpr int COLS = 64;
    __shared__ uint smem[32 * 68 + 32 * COLS];
    uint* inT = smem;
    uint* wsb = smem + 32 * 68;
    int t = threadIdx.x;
    int row0 = blockIdx.x * 64;

    if (!INBN) {
        for (int i = 0; i < 2; i++) {
            int f = t + 256 * i;
            int r = f >> 3, q = f & 7;
            int gr = row0 + r;
            uint4 v = make_uint4(0, 0, 0, 0);
            if (gr < nrows) v = *(const uint4*)&inb[(size_t)gr * 32 + q * 4];
            inT[(4 * q + 0) * 68 + r] = v.x;
            inT[(4 * q + 1) * 68 + r] = v.y;
            inT[(4 * q + 2) * 68 + r] = v.z;
            inT[(4 * q + 3) * 68 + r] = v.w;
        }
    } else {
        for (int i = 0; i < 4; i++) {
            int f = t + 256 * i;
            int r = f >> 4, q = f & 15;
            int gr = row0 + r;
            float4 v = make_float4(0.f, 0.f, 0.f, 0.f);
            if (gr < nrows) v = *(const float4*)&inf[(size_t)gr * 64 + q * 4];
            int d = 4 * q;
            float e0 = LRELU(v.x * scale[d + 0] + shift[d + 0]);
            float e1 = LRELU(v.y * scale[d + 1] + shift[d + 1]);
            float e2 = LRELU(v.z * scale[d + 2] + shift[d + 2]);
            float e3 = LRELU(v.w * scale[d + 3] + shift[d + 3]);
            inT[(2 * q + 0) * 68 + r] = pack_bf16_rne(e0, e1);
            inT[(2 * q + 1) * 68 + r] = pack_bf16_rne(e2, e3);
        }
    }
    for (int i = 0; i < 2; i++) {
        int f = (t + 256 * i) * 4;
        *(uint4*)&wsb[f] = *(const uint4*)&Wp[f];
    }
    __syncthreads();

    int rg = t >> 4, cg = t & 15;
    int r0 = rg * 4, c0 = cg * 4;
    float acc[4][4];
#pragma unroll
    for (int r = 0; r < 4; r++)
#pragma unroll
        for (int c = 0; c < 4; c++) acc[r][c] = 0.0f;

#pragma unroll 8
    for (int kp = 0; kp < 32; kp++) {
        uint4 a = *(const uint4*)&inT[kp * 68 + r0];
        uint av[4] = {a.x, a.y, a.z, a.w};
        uint4 w = *(const uint4*)&wsb[kp * COLS + c0];
        uint wv[4] = {w.x, w.y, w.z, w.w};
#pragma unroll
        for (int r = 0; r < 4; r++)
#pragma unroll
            for (int c = 0; c < 4; c++) acc[r][c] = dot2bf(av[r], wv[c], acc[r][c]);
    }

    float ps[4], ps2[4];
#pragma unroll
    for (int c = 0; c < 4; c++) ps[c] = ps2[c] = 0.0f;
    float4 bv = *(const float4*)&bias[c0];
#pragma unroll
    for (int r = 0; r < 4; r++) {
        int gr = row0 + r0 + r;
        if (gr < nrows) {
            float o0 = acc[r][0] + bv.x;
            float o1 = acc[r][1] + bv.y;
            float o2 = acc[r][2] + bv.z;
            float o3 = acc[r][3] + bv.w;
            if (OUTB) {
                uint2 pk = make_uint2(pack_bf16_rne(o0, o1), pack_bf16_rne(o2, o3));
                *(uint2*)&outb[(size_t)gr * 32 + (c0 >> 1)] = pk;
            } else {
                *(float4*)&outf[(size_t)gr * 64 + c0] = make_float4(o0, o1, o2, o3);
            }
            ps[0] += o0;
            ps2[0] += o0 * o0;
            ps[1] += o1;
            ps2[1] += o1 * o1;
            ps[2] += o2;
            ps2[2] += o2 * o2;
            ps[3] += o3;
            ps2[3] += o3 * o3;
        }
    }

    if (sums == nullptr) return;

    __syncthreads();
    float* red = (float*)smem;
    float* red2 = red + 16 * COLS;
    *(float4*)&red[rg * COLS + c0] = *(float4*)&ps[0];
    *(float4*)&red2[rg * COLS + c0] = *(float4*)&ps2[0];
    __syncthreads();
    if (t < COLS) {
        float s = 0.0f, s2 = 0.0f;
#pragma unroll
        for (int j = 0; j < 16; j++) {
            s += red[j * COLS + t];
            s2 += red2[j * COLS + t];
        }
        int slot = blockIdx.x & (NSLOT - 1);
        atomicAdd(&sums[slot * 2 * COLS + t], s);
        atomicAdd(&sums[slot * 2 * COLS + COLS + t], s2);
    }
}

// ---------- head gemm, full fp32: HF = X @ Wf1 + bf1, slotted col-stats ----------
__global__ __launch_bounds__(256, 4) void gemm_f32_head_kernel(const float* __restrict__ in,
                                                               const float* __restrict__ W,
                                                               const float* __restrict__ bias,
                                                               float* __restrict__ out,
                                                               float* __restrict__ sums,
                                                               int nrows) {
    constexpr int COLS = 128;
    __shared__ float inT[64][68];
    __shared__ float ws[64][COLS];
    int t = threadIdx.x;
    int row0 = blockIdx.x * 64;

    for (int i = 0; i < 4; i++) {
        int f = t + 256 * i;
        int r = f >> 4, ch = f & 15;
        int gr = row0 + r;
        float4 v = make_float4(0.f, 0.f, 0.f, 0.f);
        if (gr < nrows) v = *(const float4*)&in[(size_t)gr * 64 + ch * 4];
        inT[ch * 4 + 0][r] = v.x;
        inT[ch * 4 + 1][r] = v.y;
        inT[ch * 4 + 2][r] = v.z;
        inT[ch * 4 + 3][r] = v.w;
    }
    for (int i = 0; i < COLS / 16; i++) {
        int f = t + 256 * i;
        int k = f / (COLS / 4), c4 = f % (COLS / 4);
        *(float4*)&ws[k][c4 * 4] = *(const float4*)&W[(size_t)k * COLS + c4 * 4];
    }
    __syncthreads();

    int rg = t >> 4, cg = t & 15;
    int r0 = rg * 4, c0 = cg * 4;
    float acc[4][8];
#pragma unroll
    for (int r = 0; r < 4; r++)
#pragma unroll
        for (int c = 0; c < 8; c++) acc[r][c] = 0.0f;

#pragma unroll 16
    for (int k = 0; k < 64; k++) {
        float4 a = *(const float4*)&inT[k][r0];
        float ar[4] = {a.x, a.y, a.z, a.w};
#pragma unroll
        for (int jj = 0; jj < 2; jj++) {
            float4 w4 = *(const float4*)&ws[k][c0 + jj * 64];
            float wr[4] = {w4.x, w4.y, w4.z, w4.w};
#pragma unroll
            for (int r = 0; r < 4; r++)
#pragma unroll
                for (int c = 0; c < 4; c++) acc[r][jj * 4 + c] += ar[r] * wr[c];
        }
    }

    float ps[8], ps2[8];
#pragma unroll
    for (int c = 0; c < 8; c++) ps[c] = ps2[c] = 0.0f;
#pragma unroll
    for (int r = 0; r < 4; r++) {
        int gr = row0 + r0 + r;
        if (gr < nrows) {
#pragma unroll
            for (int jj = 0; jj < 2; jj++) {
                float4 bv = *(const float4*)&bias[c0 + jj * 64];
                float4 o = make_float4(acc[r][jj * 4 + 0] + bv.x, acc[r][jj * 4 + 1] + bv.y,
                                       acc[r][jj * 4 + 2] + bv.z, acc[r][jj * 4 + 3] + bv.w);
                *(float4*)&out[(size_t)gr * COLS + c0 + jj * 64] = o;
                ps[jj * 4 + 0] += o.x;
                ps2[jj * 4 + 0] += o.x * o.x;
                ps[jj * 4 + 1] += o.y;
                ps2[jj * 4 + 1] += o.y * o.y;
                ps[jj * 4 + 2] += o.z;
                ps2[jj * 4 + 2] += o.z * o.z;
                ps[jj * 4 + 3] += o.w;
                ps2[jj * 4 + 3] += o.w * o.w;
            }
        }
    }

    __syncthreads();
    float* red = &inT[0][0];
    float* red2 = red + 16 * COLS;
#pragma unroll
    for (int jj = 0; jj < 2; jj++) {
        *(float4*)&red[rg * COLS + c0 + jj * 64] = *(float4*)&ps[jj * 4];
        *(float4*)&red2[rg * COLS + c0 + jj * 64] = *(float4*)&ps2[jj * 4];
    }
    __syncthreads();
    if (t < COLS) {
        float s = 0.0f, s2 = 0.0f;
#pragma unroll
        for (int j = 0; j < 16; j++) {
            s += red[j * COLS + t];
            s2 += red2[j * COLS + t];
        }
        int slot = blockIdx.x & (NSLOT - 1);
        atomicAdd(&sums[slot * 2 * COLS + t], s);
        atomicAdd(&sums[slot * 2 * COLS + COLS + t], s2);
    }
}

// one wave per row; hf fp32 (N x 128)
__global__ void head_out_kernel(const float* __restrict__ hf, const float* __restrict__ scale,
                                const float* __restrict__ shift, const float* __restrict__ Wf2,
                                const float* __restrict__ bf2, float* __restrict__ out,
                                int nrows) {
    int gtid = blockIdx.x * blockDim.x + threadIdx.x;
    int wid = gtid >> 6;
    int l = threadIdx.x & 63;
    if (wid >= nrows) return;
    float v0 = hf[(size_t)wid * 128 + l];
    float v1 = hf[(size_t)wid * 128 + 64 + l];
    v0 = LRELU(v0 * scale[l] + shift[l]);
    v1 = LRELU(v1 * scale[64 + l] + shift[64 + l]);
    float p = v0 * Wf2[l] + v1 * Wf2[64 + l];
    for (int o = 32; o > 0; o >>= 1) p += __shfl_down(p, o);
    if (l == 0) out[wid] = p + bf2[0];
}

extern "C" void kernel_launch(void* const* d_in, const int* in_sizes, int n_in, void* d_out,
                              int out_size, void* d_ws, size_t ws_size, hipStream_t stream) {
    const float* x = (const float*)d_in[0];
    const int* esrc = (const int*)d_in[1];
    const int* edst = (const int*)d_in[2];
    const float* W1 = (const float*)d_in[3];
    const float* b1 = (const float*)d_in[4];
    const float* g1 = (const float*)d_in[5];
    const float* be1 = (const float*)d_in[6];
    const float* W2 = (const float*)d_in[7];
    const float* b2 = (const float*)d_in[8];
    const float* eps_gin = (const float*)d_in[9];
    const float* g_bn = (const float*)d_in[10];
    const float* b_bn = (const float*)d_in[11];
    const float* Wf1 = (const float*)d_in[12];
    const float* bf1 = (const float*)d_in[13];
    const float* gf = (const float*)d_in[14];
    const float* bef = (const float*)d_in[15];
    const float* Wf2 = (const float*)d_in[16];
    const float* bf2 = (const float*)d_in[17];
    float* out = (float*)d_out;

    int N = in_sizes[0] / 64;
    int E = in_sizes[1];
    int NB = (N + 255) / 256;
    float invN = 1.0f / (float)N;

    float* ws = (float*)d_ws;
    size_t ND = (size_t)N * 64;
    // region A: table bf16 (lower half) + pairs (upper, build-only); later X fp32 (full)
    uint* table = (uint*)ws;
    uint* pairs = (uint*)(ws + ND / 2);
    float* X = ws;
    float* h1 = ws + ND;               // region B: h1 fp32
    uint* agg = (uint*)(ws + 2 * ND);  // region C: agg bf16 (lower half)
    float* HF = ws + ND;               // HF fp32 spans B+C after h1/agg dead
    float* stats = ws + 3 * ND;
    float* ssarea = stats + 5 * NSLOT * 128 + NSLOT * 256;
    int* ibase = (int*)(ssarea + 5 * 128 + 256);
    int* bcnt = ibase;
    int* bcur = ibase + 512;
    int* boff = ibase + 1024;
    int* cnt = ibase + 1536;
    int* ptr = cnt + N;
    int* nbr = ptr + N;
    uint* Wp = (uint*)(nbr + E);  // 6*2048 uints packed weights

    int nzero = 5 * NSLOT * 128 + NSLOT * 256 + 5 * 128 + 256 + 512;
    zero_kernel<<<(nzero + 255) / 256, 256, 0, stream>>>(stats, nzero);

    int eb = (E + 8191) / 8192;
    bhist_kernel<<<eb, 256, 0, stream>>>(edst, bcnt, E, NB);
    bscan_kernel<<<1, 512, 0, stream>>>(bcnt, boff, bcur, NB);
    bscatter_kernel<<<eb, 256, 0, stream>>>(esrc, edst, bcur, pairs, E, NB);
    bcsr_kernel<<<NB, 256, 0, stream>>>(pairs, boff, ptr, cnt, nbr, N, NB, E);
    packw_kernel<<<(6 * 2048 + 255) / 256, 256, 0, stream>>>(W1, W2, Wp);

    int n8 = N * 8;
    int gg = (N + 63) / 64;
    int gblocks = (N * 64 + 255) / 256;
    to_bf16_kernel<<<(n8 + 255) / 256, 256, 0, stream>>>(x, table, n8);

    for (int i = 0; i < 3; i++) {
        float* st = stats + (size_t)(2 * i) * NSLOT * 128;
        float* so = stats + (size_t)(2 * i + 1) * NSLOT * 128;
        float* st_ss = ssarea + (size_t)(2 * i) * 128;
        float* so_ss = ssarea + (size_t)(2 * i + 1) * 128;
        if (i == 0) {
            gather_kernel<false><<<gblocks, 256, 0, stream>>>(table, ptr, cnt, nbr, eps_gin, i,
                                                              nullptr, nullptr, agg, N);
        } else {
            float* sp_ss = ssarea + (size_t)(2 * (i - 1) + 1) * 128;
            gather_kernel<true><<<gblocks, 256, 0, stream>>>(table, ptr, cnt, nbr, eps_gin, i,
                                                             sp_ss, sp_ss + 64, agg, N);
        }
        gemm_bf16_kernel<false, false, 6><<<gg, 256, 0, stream>>>(
            agg, nullptr, Wp + (size_t)i * 2048, b1 + (size_t)i * 64, nullptr, nullptr, nullptr,
            h1, st, N);
        finalize_kernel<<<1, 64, 0, stream>>>(st, g1 + (size_t)i * 64, be1 + (size_t)i * 64,
                                              st_ss, st_ss + 64, 64, invN);
        if (i < 2) {
            gemm_bf16_kernel<true, true, 6><<<gg, 256, 0, stream>>>(
                nullptr, h1, Wp + (size_t)(3 + i) * 2048, b2 + (size_t)i * 64, st_ss, st_ss + 64,
                table, nullptr, so, N);
            finalize_kernel<<<1, 64, 0, stream>>>(so, g_bn + (size_t)i * 64,
                                                  b_bn + (size_t)i * 64, so_ss, so_ss + 64, 64,
                                                  invN);
        } else {
            gemm_bf16_kernel<true, false, 6><<<gg, 256, 0, stream>>>(
                nullptr, h1, Wp + (size_t)(3 + i) * 2048, b2 + (size_t)i * 64, st_ss, st_ss + 64,
                nullptr, X, nullptr, N);
        }
    }

    float* sf = stats + (size_t)5 * NSLOT * 128;
    float* sf_ss = ssarea + 5 * 128;
    gemm_f32_head_kernel<<<gg, 256, 0, stream>>>(X, Wf1, bf1, HF, sf, N);
    finalize_kernel<<<1, 128, 0, stream>>>(sf, gf, bef, sf_ss, sf_ss + 128, 128, invN);
    head_out_kernel<<<(N + 3) / 4, 256, 0, stream>>>(HF, sf_ss, sf_ss + 128, Wf2, bf2, out, N);
}